// Round 6
// baseline (381.040 us; speedup 1.0000x reference)
//
#include <hip/hip_runtime.h>

typedef __bf16 bf16_t;
typedef __bf16 bf16x8 __attribute__((ext_vector_type(8)));
typedef __bf16 bf16x4 __attribute__((ext_vector_type(4)));
typedef float  f32x4  __attribute__((ext_vector_type(4)));

#define LOG2E 1.44269504088896340736f

// ---------------------------------------------------------------- helpers
__device__ __forceinline__ void gload_lds16(const void* g, void* l) {
  __builtin_amdgcn_global_load_lds(
      (const __attribute__((address_space(1))) void*)g,
      (__attribute__((address_space(3))) void*)l, 16, 0, 0);
}

__device__ __forceinline__ void store_c(float* p, float v)  { *p = v; }
__device__ __forceinline__ void store_c(bf16_t* p, float v) { *p = (bf16_t)v; }

// ---------------------------------------------------------------- cast fp32 -> bf16
__global__ __launch_bounds__(256) void cast_kernel(const float* __restrict__ in,
                                                   bf16_t* __restrict__ out, int n4) {
  int i = blockIdx.x * 256 + threadIdx.x;
  const int stride = gridDim.x * 256;
  for (; i < n4; i += stride) {
    f32x4 v = *(const f32x4*)(in + (size_t)i * 4);
    bf16x4 o;
#pragma unroll
    for (int j = 0; j < 4; ++j) o[j] = (bf16_t)v[j];
    *(bf16x4*)(out + (size_t)i * 4) = o;
  }
}

// ---------------------------------------------------------------- GEMM  C[M][N] = A[M][K] * B[N][K]^T
template <typename OutT>
__global__ __launch_bounds__(256) void gemm_bt(const bf16_t* __restrict__ A,
                                               const bf16_t* __restrict__ B,
                                               OutT* __restrict__ C,
                                               int M, int N, int K) {
  __shared__ bf16_t As[128 * 32];
  __shared__ bf16_t Bs[128 * 32];
  const int tid  = threadIdx.x;
  const int lane = tid & 63;
  const int wid  = tid >> 6;
  const int wm = wid >> 1, wn = wid & 1;
  const size_t m0 = (size_t)blockIdx.y * 128;
  const size_t n0 = (size_t)blockIdx.x * 128;

  f32x4 acc[4][4] = {};

  for (int k0 = 0; k0 < K; k0 += 32) {
#pragma unroll
    for (int j = 0; j < 2; ++j) {
      const int c = tid + j * 256;
      const int r = c >> 2;
      const int kp = (c & 3) * 8;
      gload_lds16(A + (m0 + r) * K + k0 + kp, As + (size_t)c * 8);
      gload_lds16(B + (n0 + r) * K + k0 + kp, Bs + (size_t)c * 8);
    }
    __syncthreads();

    const int kk = (lane >> 4) * 8;
    const int rs = lane & 15;
    bf16x8 af[4], bfv[4];
#pragma unroll
    for (int t = 0; t < 4; ++t) {
      af[t]  = *(const bf16x8*)(As + (wm * 64 + t * 16 + rs) * 32 + kk);
      bfv[t] = *(const bf16x8*)(Bs + (wn * 64 + t * 16 + rs) * 32 + kk);
    }
#pragma unroll
    for (int mt = 0; mt < 4; ++mt)
#pragma unroll
      for (int nt = 0; nt < 4; ++nt)
        acc[mt][nt] = __builtin_amdgcn_mfma_f32_16x16x32_bf16(af[mt], bfv[nt], acc[mt][nt], 0, 0, 0);
    __syncthreads();
  }

#pragma unroll
  for (int mt = 0; mt < 4; ++mt)
#pragma unroll
    for (int nt = 0; nt < 4; ++nt)
#pragma unroll
      for (int r = 0; r < 4; ++r) {
        size_t row = m0 + wm * 64 + mt * 16 + (lane >> 4) * 4 + r;
        size_t col = n0 + wn * 64 + nt * 16 + (lane & 15);
        store_c(C + row * N + col, acc[mt][nt][r]);
      }
}

// ---------------------------------------------------------------- RoPE + reorg
__global__ __launch_bounds__(256) void rope_reorg(const bf16_t* __restrict__ qkv,
                                                  const float* __restrict__ cosT,
                                                  const float* __restrict__ sinT,
                                                  bf16_t* __restrict__ Q,
                                                  bf16_t* __restrict__ Kd,
                                                  bf16_t* __restrict__ Vt) {
  __shared__ bf16_t T[64 * 72];
  const int blk  = blockIdx.x;
  const int sblk = blk & 31;
  const int hh   = (blk >> 5) % 48;
  const int b    = blk / (32 * 48);
  const int s0   = sblk * 64;
  const int tid  = threadIdx.x;

  if (hh < 32) {
    const bool isq = hh < 16;
    const int h = isq ? hh : hh - 16;
    bf16_t* dst = (isq ? Q : Kd) + (size_t)(b * 16 + h) * 2048 * 64;
    for (int u = tid; u < 512; u += 256) {
      const int s = u >> 3, oct = u & 7;
      const size_t src = ((size_t)(b * 2048) + s0 + s) * 3072 + hh * 64;
      bf16x8 x = *(const bf16x8*)(qkv + src + oct * 8);
      bf16x8 y = *(const bf16x8*)(qkv + src + ((oct * 8) ^ 32));
      const float* cp = cosT + (size_t)(s0 + s) * 64 + oct * 8;
      const float* sp = sinT + (size_t)(s0 + s) * 64 + oct * 8;
      const float sgn = (oct < 4) ? -1.f : 1.f;
      bf16x8 ov;
#pragma unroll
      for (int j = 0; j < 8; ++j) {
        float xv = (float)x[j], yv = (float)y[j];
        ov[j] = (bf16_t)(xv * cp[j] + sgn * yv * sp[j]);
      }
      *(bf16x8*)(dst + (size_t)(s0 + s) * 64 + oct * 8) = ov;
    }
  } else {
    const int hv = hh - 32;
    for (int u = tid; u < 512; u += 256) {
      const int s = u >> 3, oct = u & 7;
      *(bf16x8*)(&T[s * 72 + oct * 8]) =
          *(const bf16x8*)(qkv + ((size_t)(b * 2048) + s0 + s) * 3072 + hh * 64 + oct * 8);
    }
    __syncthreads();
    bf16_t* dst = Vt + (size_t)(b * 16 + hv) * 64 * 2048;
    for (int u = tid; u < 512; u += 256) {
      const int d = u >> 3, soct = u & 7;
      bf16x8 w;
#pragma unroll
      for (int j = 0; j < 8; ++j) w[j] = T[(soct * 8 + j) * 72 + d];
      *(bf16x8*)(dst + (size_t)d * 2048 + s0 + soct * 8) = w;
    }
  }
}

// ---------------------------------------------------------------- flash attention v4
// R2-verified 16x16x32 fragment math; KVBLK=64; K/V direct from global
// (L2-resident, no LDS staging, NO barriers); P re-layout via per-wave
// private LDS tile (in-wave lgkmcnt fence only). Heavy q-tiles first.
__global__ __launch_bounds__(256) void attn_kernel(const bf16_t* __restrict__ Q,
                                                   const bf16_t* __restrict__ Kt,
                                                   const bf16_t* __restrict__ Vt,
                                                   bf16_t* __restrict__ O) {
  const int qblk = 31 - blockIdx.x;         // heavy first
  const int h    = blockIdx.y;
  const int b    = blockIdx.z;
  const int tid  = threadIdx.x;
  const int lane = tid & 63;
  const int wid  = tid >> 6;
  const int bh   = b * 16 + h;
  const bf16_t* Qb = Q  + (size_t)bh * 2048 * 64;
  const bf16_t* Kb = Kt + (size_t)bh * 2048 * 64;
  const bf16_t* Vb = Vt + (size_t)bh * 64 * 2048;

  __shared__ bf16_t Ps[4][16 * 72];         // per-wave P tile [16 q][64 k]

  const int q0  = qblk * 64 + wid * 16;     // wave's 16 query rows
  const int l15 = lane & 15;
  const int g   = lane >> 4;
  const int dd  = g * 8;
  const int qmax = q0 + 15;
  const float SC = 0.125f * LOG2E;

  // Q A-fragments (verified R2 layout): lane holds Q[q0+l15][dd..dd+7 (+32)]
  bf16x8 qf0 = *(const bf16x8*)(Qb + (size_t)(q0 + l15) * 64 + dd);
  bf16x8 qf1 = *(const bf16x8*)(Qb + (size_t)(q0 + l15) * 64 + 32 + dd);

  f32x4 o[4] = {};
  float mr[4], lr[4];
#pragma unroll
  for (int r = 0; r < 4; ++r) { mr[r] = -3.0e38f; lr[r] = 0.f; }

  for (int kv0 = 0; kv0 <= qmax; kv0 += 64) {
    // ---- S = Q K^T over 4 x 16-key slices (K read direct from global)
    f32x4 st[4];
    bool act[4];
#pragma unroll
    for (int kt = 0; kt < 4; ++kt) {
      act[kt] = (kv0 + kt * 16 <= qmax);
      if (act[kt]) {
        const bf16_t* kp = Kb + (size_t)(kv0 + kt * 16 + l15) * 64;
        bf16x8 kf0 = *(const bf16x8*)(kp + dd);
        bf16x8 kf1 = *(const bf16x8*)(kp + 32 + dd);
        f32x4 acc = {};
        acc = __builtin_amdgcn_mfma_f32_16x16x32_bf16(qf0, kf0, acc, 0, 0, 0);
        acc = __builtin_amdgcn_mfma_f32_16x16x32_bf16(qf1, kf1, acc, 0, 0, 0);
        st[kt] = acc;
      }
    }

    // ---- causal mask (only the diagonal-crossing tile needs it)
    const bool need_mask = (kv0 + 63 > q0);
    if (need_mask) {
#pragma unroll
      for (int kt = 0; kt < 4; ++kt) {
        if (!act[kt]) continue;
#pragma unroll
        for (int r = 0; r < 4; ++r) {
          const int kg = kv0 + kt * 16 + l15;
          const int qg = q0 + g * 4 + r;
          if (kg > qg) st[kt][r] = -3.0e38f;
        }
      }
    }

    // ---- online softmax (row = q lives across the 16-lane group)
    float p[4][4];
    float al[4];
#pragma unroll
    for (int r = 0; r < 4; ++r) {
      float mb = -3.0e38f;
#pragma unroll
      for (int kt = 0; kt < 4; ++kt)
        if (act[kt]) mb = fmaxf(mb, st[kt][r]);
      mb = fmaxf(mb, __shfl_xor(mb, 1));
      mb = fmaxf(mb, __shfl_xor(mb, 2));
      mb = fmaxf(mb, __shfl_xor(mb, 4));
      mb = fmaxf(mb, __shfl_xor(mb, 8));
      const float mn = fmaxf(mr[r], mb);
      al[r] = __builtin_amdgcn_exp2f((mr[r] - mn) * SC);
      const float mc = mn * SC;
      float lb = 0.f;
#pragma unroll
      for (int kt = 0; kt < 4; ++kt) {
        if (act[kt]) {
          p[kt][r] = __builtin_amdgcn_exp2f(__builtin_fmaf(st[kt][r], SC, -mc));
          lb += p[kt][r];
        } else {
          p[kt][r] = 0.f;
        }
      }
      lb += __shfl_xor(lb, 1);
      lb += __shfl_xor(lb, 2);
      lb += __shfl_xor(lb, 4);
      lb += __shfl_xor(lb, 8);
      lr[r] = lr[r] * al[r] + lb;
      mr[r] = mn;
    }
#pragma unroll
    for (int dt = 0; dt < 4; ++dt)
#pragma unroll
      for (int r = 0; r < 4; ++r) o[dt][r] *= al[r];

    // ---- P -> per-wave LDS tile (C-frag -> A-frag re-layout)
#pragma unroll
    for (int kt = 0; kt < 4; ++kt)
#pragma unroll
      for (int r = 0; r < 4; ++r)
        Ps[wid][(g * 4 + r) * 72 + kt * 16 + l15] = (bf16_t)p[kt][r];

    asm volatile("s_waitcnt lgkmcnt(0)" ::: "memory");
    __builtin_amdgcn_sched_barrier(0);

    // ---- O += P V  (V^T read direct from global)
#pragma unroll
    for (int half = 0; half < 2; ++half) {
      if (kv0 + half * 32 > qmax) break;    // second half entirely masked
      bf16x8 pa = *(const bf16x8*)(&Ps[wid][l15 * 72 + half * 32 + dd]);
#pragma unroll
      for (int dt = 0; dt < 4; ++dt) {
        bf16x8 vf = *(const bf16x8*)(Vb + (size_t)(dt * 16 + l15) * 2048 + kv0 + half * 32 + dd);
        o[dt] = __builtin_amdgcn_mfma_f32_16x16x32_bf16(pa, vf, o[dt], 0, 0, 0);
      }
    }
  }

  // ---- epilogue
#pragma unroll
  for (int r = 0; r < 4; ++r) {
    const float inv = 1.f / lr[r];
    size_t srow = (size_t)b * 2048 + q0 + g * 4 + r;
#pragma unroll
    for (int dt = 0; dt < 4; ++dt)
      O[srow * 1024 + h * 64 + dt * 16 + l15] = (bf16_t)(o[dt][r] * inv);
  }
}

// ---------------------------------------------------------------- launch
extern "C" void kernel_launch(void* const* d_in, const int* in_sizes, int n_in,
                              void* d_out, int out_size, void* d_ws, size_t ws_size,
                              hipStream_t stream) {
  const float* hs   = (const float*)d_in[0];   // [2][2048][1024]
  const float* cosT = (const float*)d_in[1];   // [2048][64]
  const float* sinT = (const float*)d_in[2];   // [2048][64]
  const float* wqkv = (const float*)d_in[3];   // [3072][1024]
  const float* wo   = (const float*)d_in[4];   // [1024][1024]
  float* out = (float*)d_out;                  // [2][2048][1024]

  char* ws = (char*)d_ws;
  bf16_t* hs_b   = (bf16_t*)(ws);
  bf16_t* wqkv_b = (bf16_t*)(ws + 8388608);
  bf16_t* wo_b   = (bf16_t*)(ws + 14680064);
  bf16_t* qkv    = (bf16_t*)(ws + 16777216);
  bf16_t* Qb     = (bf16_t*)(ws + 41943040);
  bf16_t* Kb     = (bf16_t*)(ws + 50331648);
  bf16_t* Vtb    = (bf16_t*)(ws + 58720256);
  bf16_t* aout   = (bf16_t*)(ws + 67108864);

  cast_kernel<<<2048, 256, 0, stream>>>(hs,   hs_b,   4194304 / 4);
  cast_kernel<<<1024, 256, 0, stream>>>(wqkv, wqkv_b, 3145728 / 4);
  cast_kernel<<<512,  256, 0, stream>>>(wo,   wo_b,   1048576 / 4);

  gemm_bt<bf16_t><<<dim3(24, 32), 256, 0, stream>>>(hs_b, wqkv_b, qkv, 4096, 3072, 1024);

  rope_reorg<<<3072, 256, 0, stream>>>(qkv, cosT, sinT, Qb, Kb, Vtb);

  attn_kernel<<<dim3(32, 16, 2), 256, 0, stream>>>(Qb, Kb, Vtb, aout);

  gemm_bt<float><<<dim3(8, 32), 256, 0, stream>>>(aout, wo_b, out, 4096, 1024, 1024);
}

// Round 7
// 276.908 us; speedup vs baseline: 1.3761x; 1.3761x over previous
//
#include <hip/hip_runtime.h>

typedef __bf16 bf16_t;
typedef __bf16 bf16x8 __attribute__((ext_vector_type(8)));
typedef __bf16 bf16x4 __attribute__((ext_vector_type(4)));
typedef float  f32x4  __attribute__((ext_vector_type(4)));

#define LOG2E 1.44269504088896340736f

// ---------------------------------------------------------------- helpers
__device__ __forceinline__ void gload_lds16(const void* g, void* l) {
  __builtin_amdgcn_global_load_lds(
      (const __attribute__((address_space(1))) void*)g,
      (__attribute__((address_space(3))) void*)l, 16, 0, 0);
}

__device__ __forceinline__ void store_c(float* p, float v)  { *p = v; }
__device__ __forceinline__ void store_c(bf16_t* p, float v) { *p = (bf16_t)v; }

// ---------------------------------------------------------------- cast fp32 -> bf16
__global__ __launch_bounds__(256) void cast_kernel(const float* __restrict__ in,
                                                   bf16_t* __restrict__ out, int n4) {
  int i = blockIdx.x * 256 + threadIdx.x;
  const int stride = gridDim.x * 256;
  for (; i < n4; i += stride) {
    f32x4 v = *(const f32x4*)(in + (size_t)i * 4);
    bf16x4 o;
#pragma unroll
    for (int j = 0; j < 4; ++j) o[j] = (bf16_t)v[j];
    *(bf16x4*)(out + (size_t)i * 4) = o;
  }
}

// ---------------------------------------------------------------- GEMM  C[M][N] = A[M][K] * B[N][K]^T
template <typename OutT>
__global__ __launch_bounds__(256) void gemm_bt(const bf16_t* __restrict__ A,
                                               const bf16_t* __restrict__ B,
                                               OutT* __restrict__ C,
                                               int M, int N, int K) {
  __shared__ bf16_t As[128 * 32];
  __shared__ bf16_t Bs[128 * 32];
  const int tid  = threadIdx.x;
  const int lane = tid & 63;
  const int wid  = tid >> 6;
  const int wm = wid >> 1, wn = wid & 1;
  const size_t m0 = (size_t)blockIdx.y * 128;
  const size_t n0 = (size_t)blockIdx.x * 128;

  f32x4 acc[4][4] = {};

  for (int k0 = 0; k0 < K; k0 += 32) {
#pragma unroll
    for (int j = 0; j < 2; ++j) {
      const int c = tid + j * 256;
      const int r = c >> 2;
      const int kp = (c & 3) * 8;
      gload_lds16(A + (m0 + r) * K + k0 + kp, As + (size_t)c * 8);
      gload_lds16(B + (n0 + r) * K + k0 + kp, Bs + (size_t)c * 8);
    }
    __syncthreads();

    const int kk = (lane >> 4) * 8;
    const int rs = lane & 15;
    bf16x8 af[4], bfv[4];
#pragma unroll
    for (int t = 0; t < 4; ++t) {
      af[t]  = *(const bf16x8*)(As + (wm * 64 + t * 16 + rs) * 32 + kk);
      bfv[t] = *(const bf16x8*)(Bs + (wn * 64 + t * 16 + rs) * 32 + kk);
    }
#pragma unroll
    for (int mt = 0; mt < 4; ++mt)
#pragma unroll
      for (int nt = 0; nt < 4; ++nt)
        acc[mt][nt] = __builtin_amdgcn_mfma_f32_16x16x32_bf16(af[mt], bfv[nt], acc[mt][nt], 0, 0, 0);
    __syncthreads();
  }

#pragma unroll
  for (int mt = 0; mt < 4; ++mt)
#pragma unroll
    for (int nt = 0; nt < 4; ++nt)
#pragma unroll
      for (int r = 0; r < 4; ++r) {
        size_t row = m0 + wm * 64 + mt * 16 + (lane >> 4) * 4 + r;
        size_t col = n0 + wn * 64 + nt * 16 + (lane & 15);
        store_c(C + row * N + col, acc[mt][nt][r]);
      }
}

// ---------------------------------------------------------------- RoPE + reorg
__global__ __launch_bounds__(256) void rope_reorg(const bf16_t* __restrict__ qkv,
                                                  const float* __restrict__ cosT,
                                                  const float* __restrict__ sinT,
                                                  bf16_t* __restrict__ Q,
                                                  bf16_t* __restrict__ Kd,
                                                  bf16_t* __restrict__ Vt) {
  __shared__ bf16_t T[64 * 72];
  const int blk  = blockIdx.x;
  const int sblk = blk & 31;
  const int hh   = (blk >> 5) % 48;
  const int b    = blk / (32 * 48);
  const int s0   = sblk * 64;
  const int tid  = threadIdx.x;

  if (hh < 32) {
    const bool isq = hh < 16;
    const int h = isq ? hh : hh - 16;
    bf16_t* dst = (isq ? Q : Kd) + (size_t)(b * 16 + h) * 2048 * 64;
    for (int u = tid; u < 512; u += 256) {
      const int s = u >> 3, oct = u & 7;
      const size_t src = ((size_t)(b * 2048) + s0 + s) * 3072 + hh * 64;
      bf16x8 x = *(const bf16x8*)(qkv + src + oct * 8);
      bf16x8 y = *(const bf16x8*)(qkv + src + ((oct * 8) ^ 32));
      const float* cp = cosT + (size_t)(s0 + s) * 64 + oct * 8;
      const float* sp = sinT + (size_t)(s0 + s) * 64 + oct * 8;
      const float sgn = (oct < 4) ? -1.f : 1.f;
      bf16x8 ov;
#pragma unroll
      for (int j = 0; j < 8; ++j) {
        float xv = (float)x[j], yv = (float)y[j];
        ov[j] = (bf16_t)(xv * cp[j] + sgn * yv * sp[j]);
      }
      *(bf16x8*)(dst + (size_t)(s0 + s) * 64 + oct * 8) = ov;
    }
  } else {
    const int hv = hh - 32;
    for (int u = tid; u < 512; u += 256) {
      const int s = u >> 3, oct = u & 7;
      *(bf16x8*)(&T[s * 72 + oct * 8]) =
          *(const bf16x8*)(qkv + ((size_t)(b * 2048) + s0 + s) * 3072 + hh * 64 + oct * 8);
    }
    __syncthreads();
    bf16_t* dst = Vt + (size_t)(b * 16 + hv) * 64 * 2048;
    for (int u = tid; u < 512; u += 256) {
      const int d = u >> 3, soct = u & 7;
      bf16x8 w;
#pragma unroll
      for (int j = 0; j < 8; ++j) w[j] = T[(soct * 8 + j) * 72 + d];
      *(bf16x8*)(dst + (size_t)d * 2048 + s0 + soct * 8) = w;
    }
  }
}

// ---------------------------------------------------------------- flash attention v5
// v4 verified math + two latency fixes:
//  (1) XCD-locality: 4 bh per XCD (bid&7 -> XCD under round-robin dispatch);
//      per-XCD K+V working set 2MB fits the 4MB L2 -> loads are L2 hits.
//  (2) Register prefetch: K double-buffered one tile ahead; V issued at tile
//      top so its latency hides under QK^T+softmax. No barriers, LDS only for
//      the per-wave P re-layout tile.
__global__ __launch_bounds__(256) void attn_kernel(const bf16_t* __restrict__ Q,
                                                   const bf16_t* __restrict__ Kt,
                                                   const bf16_t* __restrict__ Vt,
                                                   bf16_t* __restrict__ O) {
  const int bid  = blockIdx.x;              // 1024 blocks, 1D
  const int xcd  = bid & 7;
  const int idx  = bid >> 3;
  const int bh   = xcd * 4 + (idx & 3);     // 4 bh per XCD
  const int qblk = 31 - (idx >> 2);         // heavy first
  const int b    = bh >> 4;
  const int h    = bh & 15;
  const int tid  = threadIdx.x;
  const int lane = tid & 63;
  const int wid  = tid >> 6;
  const bf16_t* Qb = Q  + (size_t)bh * 2048 * 64;
  const bf16_t* Kb = Kt + (size_t)bh * 2048 * 64;
  const bf16_t* Vb = Vt + (size_t)bh * 64 * 2048;

  __shared__ bf16_t Ps[4][16 * 72];         // per-wave P tile [16 q][64 k]

  const int q0  = qblk * 64 + wid * 16;     // wave's 16 query rows
  const int l15 = lane & 15;
  const int g   = lane >> 4;
  const int dd  = g * 8;
  const int qmax = q0 + 15;
  const int ntiles = qmax / 64 + 1;         // 64-key tiles
  const float SC = 0.125f * LOG2E;

  // Q A-fragments (verified layout): lane holds Q[q0+l15][dd..dd+7 (+32)]
  bf16x8 qf0 = *(const bf16x8*)(Qb + (size_t)(q0 + l15) * 64 + dd);
  bf16x8 qf1 = *(const bf16x8*)(Qb + (size_t)(q0 + l15) * 64 + 32 + dd);

  f32x4 o[4] = {};
  float mr[4], lr[4];
#pragma unroll
  for (int r = 0; r < 4; ++r) { mr[r] = -3.0e38f; lr[r] = 0.f; }

  auto prefK = [&](int tt, bf16x8 (&kf)[4][2]) {
    if (tt >= ntiles) return;
    const int kv0 = tt * 64;
#pragma unroll
    for (int kt = 0; kt < 4; ++kt) {        // rows <= 2047 always (in-bounds)
      const bf16_t* kp = Kb + (size_t)(kv0 + kt * 16 + l15) * 64;
      kf[kt][0] = *(const bf16x8*)(kp + dd);
      kf[kt][1] = *(const bf16x8*)(kp + 32 + dd);
    }
  };
  auto prefV = [&](int tt, bf16x8 (&vf)[2][4]) {
    if (tt >= ntiles) return;
    const int kv0 = tt * 64;
#pragma unroll
    for (int half = 0; half < 2; ++half)
#pragma unroll
      for (int dt = 0; dt < 4; ++dt)
        vf[half][dt] = *(const bf16x8*)(Vb + (size_t)(dt * 16 + l15) * 2048 + kv0 + half * 32 + dd);
  };

  auto compute = [&](bf16x8 (&kf)[4][2], bf16x8 (&vf)[2][4], int kv0) {
    // ---- S = Q K^T over 4 x 16-key slices (frags preloaded)
    f32x4 st[4];
#pragma unroll
    for (int kt = 0; kt < 4; ++kt) {
      f32x4 acc = {};
      acc = __builtin_amdgcn_mfma_f32_16x16x32_bf16(qf0, kf[kt][0], acc, 0, 0, 0);
      acc = __builtin_amdgcn_mfma_f32_16x16x32_bf16(qf1, kf[kt][1], acc, 0, 0, 0);
      st[kt] = acc;
    }

    // ---- causal mask (also zeroes slices beyond qmax on the ragged tile)
    if (kv0 + 63 > q0) {
#pragma unroll
      for (int kt = 0; kt < 4; ++kt)
#pragma unroll
        for (int r = 0; r < 4; ++r) {
          const int kg = kv0 + kt * 16 + l15;
          const int qg = q0 + g * 4 + r;
          if (kg > qg) st[kt][r] = -3.0e38f;
        }
    }

    // ---- online softmax (row = q lives across the 16-lane group)
    float p[4][4];
    float al[4];
#pragma unroll
    for (int r = 0; r < 4; ++r) {
      float mb = fmaxf(fmaxf(st[0][r], st[1][r]), fmaxf(st[2][r], st[3][r]));
      mb = fmaxf(mb, __shfl_xor(mb, 1));
      mb = fmaxf(mb, __shfl_xor(mb, 2));
      mb = fmaxf(mb, __shfl_xor(mb, 4));
      mb = fmaxf(mb, __shfl_xor(mb, 8));
      const float mn = fmaxf(mr[r], mb);
      al[r] = __builtin_amdgcn_exp2f((mr[r] - mn) * SC);
      const float mc = mn * SC;
      float lb = 0.f;
#pragma unroll
      for (int kt = 0; kt < 4; ++kt) {
        p[kt][r] = __builtin_amdgcn_exp2f(__builtin_fmaf(st[kt][r], SC, -mc));
        lb += p[kt][r];
      }
      lb += __shfl_xor(lb, 1);
      lb += __shfl_xor(lb, 2);
      lb += __shfl_xor(lb, 4);
      lb += __shfl_xor(lb, 8);
      lr[r] = lr[r] * al[r] + lb;
      mr[r] = mn;
    }
#pragma unroll
    for (int dt = 0; dt < 4; ++dt)
#pragma unroll
      for (int r = 0; r < 4; ++r) o[dt][r] *= al[r];

    // ---- P -> per-wave LDS tile (C-frag -> A-frag re-layout)
#pragma unroll
    for (int kt = 0; kt < 4; ++kt)
#pragma unroll
      for (int r = 0; r < 4; ++r)
        Ps[wid][(g * 4 + r) * 72 + kt * 16 + l15] = (bf16_t)p[kt][r];

    asm volatile("s_waitcnt lgkmcnt(0)" ::: "memory");
    __builtin_amdgcn_sched_barrier(0);

    // ---- O += P V  (V frags preloaded at tile top)
#pragma unroll
    for (int half = 0; half < 2; ++half) {
      if (kv0 + half * 32 > qmax) break;    // second half entirely masked
      bf16x8 pa = *(const bf16x8*)(&Ps[wid][l15 * 72 + half * 32 + dd]);
#pragma unroll
      for (int dt = 0; dt < 4; ++dt)
        o[dt] = __builtin_amdgcn_mfma_f32_16x16x32_bf16(pa, vf[half][dt], o[dt], 0, 0, 0);
    }
  };

  bf16x8 ka[4][2], kb2[4][2], vcur[2][4];
  prefK(0, ka);
  for (int t = 0; t < ntiles; t += 2) {
    prefK(t + 1, kb2);                      // next-tile K in flight
    prefV(t, vcur);                         // this-tile V in flight during QK+softmax
    compute(ka, vcur, t * 64);
    prefK(t + 2, ka);
    prefV(t + 1, vcur);
    if (t + 1 < ntiles) compute(kb2, vcur, (t + 1) * 64);
  }

  // ---- epilogue
#pragma unroll
  for (int r = 0; r < 4; ++r) {
    const float inv = 1.f / lr[r];
    size_t srow = (size_t)b * 2048 + q0 + g * 4 + r;
#pragma unroll
    for (int dt = 0; dt < 4; ++dt)
      O[srow * 1024 + h * 64 + dt * 16 + l15] = (bf16_t)(o[dt][r] * inv);
  }
}

// ---------------------------------------------------------------- launch
extern "C" void kernel_launch(void* const* d_in, const int* in_sizes, int n_in,
                              void* d_out, int out_size, void* d_ws, size_t ws_size,
                              hipStream_t stream) {
  const float* hs   = (const float*)d_in[0];   // [2][2048][1024]
  const float* cosT = (const float*)d_in[1];   // [2048][64]
  const float* sinT = (const float*)d_in[2];   // [2048][64]
  const float* wqkv = (const float*)d_in[3];   // [3072][1024]
  const float* wo   = (const float*)d_in[4];   // [1024][1024]
  float* out = (float*)d_out;                  // [2][2048][1024]

  char* ws = (char*)d_ws;
  bf16_t* hs_b   = (bf16_t*)(ws);
  bf16_t* wqkv_b = (bf16_t*)(ws + 8388608);
  bf16_t* wo_b   = (bf16_t*)(ws + 14680064);
  bf16_t* qkv    = (bf16_t*)(ws + 16777216);
  bf16_t* Qb     = (bf16_t*)(ws + 41943040);
  bf16_t* Kb     = (bf16_t*)(ws + 50331648);
  bf16_t* Vtb    = (bf16_t*)(ws + 58720256);
  bf16_t* aout   = (bf16_t*)(ws + 67108864);

  cast_kernel<<<2048, 256, 0, stream>>>(hs,   hs_b,   4194304 / 4);
  cast_kernel<<<1024, 256, 0, stream>>>(wqkv, wqkv_b, 3145728 / 4);
  cast_kernel<<<512,  256, 0, stream>>>(wo,   wo_b,   1048576 / 4);

  gemm_bt<bf16_t><<<dim3(24, 32), 256, 0, stream>>>(hs_b, wqkv_b, qkv, 4096, 3072, 1024);

  rope_reorg<<<3072, 256, 0, stream>>>(qkv, cosT, sinT, Qb, Kb, Vtb);

  attn_kernel<<<1024, 256, 0, stream>>>(Qb, Kb, Vtb, aout);

  gemm_bt<float><<<dim3(8, 32), 256, 0, stream>>>(aout, wo_b, out, 4096, 1024, 1024);
}